// Round 1
// baseline (108.740 us; speedup 1.0000x reference)
//
#include <hip/hip_runtime.h>
#include <math.h>

#define B_SZ 16
#define K_PTS 4096
#define ALPHA 1.1f

// Phase 1: for each point i, running top-3 smallest squared distances over all j
// (self included; it lands at m0 and is dropped, matching the reference's
// top_k(k+1) then drop-first). value[b,i] = (m1+m2)/2 written into the mask
// region of d_out (65536 floats, exactly B*K).
__global__ __launch_bounds__(256) void sor_value_kernel(
    const float* __restrict__ x, float* __restrict__ value)
{
    __shared__ float4 pts[K_PTS];   // 64 KiB: (x, y, z, ||x||^2)
    const int b = blockIdx.y;
    const float* xb = x + (size_t)b * K_PTS * 3;

    for (int p = threadIdx.x; p < K_PTS; p += 256) {
        float a0 = xb[p * 3 + 0];
        float a1 = xb[p * 3 + 1];
        float a2 = xb[p * 3 + 2];
        pts[p] = make_float4(a0, a1, a2, a0 * a0 + a1 * a1 + a2 * a2);
    }
    __syncthreads();

    const int i = blockIdx.x * 256 + threadIdx.x;
    const float4 pi = pts[i];
    float m0 = 3.0e38f, m1 = 3.0e38f, m2 = 3.0e38f;

    #pragma unroll 8
    for (int j = 0; j < K_PTS; ++j) {
        float4 pj = pts[j];
        float dot = pi.x * pj.x + pi.y * pj.y + pi.z * pj.z;
        float d = (pi.w - 2.0f * dot) + pj.w;   // xx_i + (-2 dot) + xx_j, like ref
        // branchless sorted insert into (m0 <= m1 <= m2):
        m2 = __builtin_amdgcn_fmed3f(d, m1, m2);   // min(m2, max(m1, d))
        m1 = __builtin_amdgcn_fmed3f(d, m0, m1);   // min(m1, max(m0, d))
        m0 = fminf(d, m0);
    }
    value[b * K_PTS + i] = 0.5f * (m1 + m2);
}

// Phase 2: one block per batch. Two-pass mean/std (ddof=1) over the 4096
// values, then threshold, mask, and sel_pc write. Overwrites the value slots
// with the 0/1 mask (each thread reads its own values into registers first).
__global__ __launch_bounds__(1024) void sor_mask_kernel(
    const float* __restrict__ x, float* __restrict__ out)
{
    const int b = blockIdx.x;
    const int tid = threadIdx.x;
    float* value = out + (size_t)B_SZ * K_PTS * 3;   // mask region doubles as value buffer
    float* selpc = out;

    __shared__ float red[16];
    __shared__ float sh_mean, sh_thr;

    float v[4];
    float s = 0.0f;
    #pragma unroll
    for (int k = 0; k < 4; ++k) {
        v[k] = value[b * K_PTS + tid + k * 1024];
        s += v[k];
    }
    #pragma unroll
    for (int off = 32; off > 0; off >>= 1) s += __shfl_down(s, off, 64);
    if ((tid & 63) == 0) red[tid >> 6] = s;
    __syncthreads();
    if (tid == 0) {
        float t = 0.0f;
        for (int w = 0; w < 16; ++w) t += red[w];
        sh_mean = t * (1.0f / (float)K_PTS);
    }
    __syncthreads();
    const float mean = sh_mean;

    float q = 0.0f;
    #pragma unroll
    for (int k = 0; k < 4; ++k) { float dv = v[k] - mean; q += dv * dv; }
    #pragma unroll
    for (int off = 32; off > 0; off >>= 1) q += __shfl_down(q, off, 64);
    if ((tid & 63) == 0) red[tid >> 6] = q;
    __syncthreads();
    if (tid == 0) {
        float t = 0.0f;
        for (int w = 0; w < 16; ++w) t += red[w];
        sh_thr = mean + ALPHA * sqrtf(t / (float)(K_PTS - 1));
    }
    __syncthreads();
    const float thr = sh_thr;

    #pragma unroll
    for (int k = 0; k < 4; ++k) {
        const int i = tid + k * 1024;
        const bool keep = v[k] <= thr;
        value[b * K_PTS + i] = keep ? 1.0f : 0.0f;
        const size_t base = ((size_t)b * K_PTS + i) * 3;
        float x0 = x[base + 0];
        float x1 = x[base + 1];
        float x2 = x[base + 2];
        selpc[base + 0] = keep ? x0 : 0.0f;
        selpc[base + 1] = keep ? x1 : 0.0f;
        selpc[base + 2] = keep ? x2 : 0.0f;
    }
}

extern "C" void kernel_launch(void* const* d_in, const int* in_sizes, int n_in,
                              void* d_out, int out_size, void* d_ws, size_t ws_size,
                              hipStream_t stream)
{
    const float* x = (const float*)d_in[0];
    float* out = (float*)d_out;
    float* value = out + (size_t)B_SZ * K_PTS * 3;

    dim3 g1(K_PTS / 256, B_SZ);
    sor_value_kernel<<<g1, 256, 0, stream>>>(x, value);
    sor_mask_kernel<<<B_SZ, 1024, 0, stream>>>(x, out);
}

// Round 2
// 51.881 us; speedup vs baseline: 2.0959x; 2.0959x over previous
//
#include <hip/hip_runtime.h>
#include <math.h>

#define B_SZ 16
#define K_PTS 4096
#define ALPHA 1.1f

#define JS 8                 // j-split factor (partial results per point)
#define JT (K_PTS / JS)      // 512 points per j-tile
#define ICH 1024             // i-points covered per block
#define IPT 4                // i-points per thread (ILP)
#define THR 256

#define BIGF 3.0e38f

__device__ __forceinline__ void insert3(float d, float& m0, float& m1, float& m2) {
    // branchless sorted insert, keeps 3 smallest (m0 <= m1 <= m2)
    m2 = __builtin_amdgcn_fmed3f(d, m1, m2);
    m1 = __builtin_amdgcn_fmed3f(d, m0, m1);
    m0 = fminf(d, m0);
}

// Partial top-3 of shifted distance d' = -2<xi,xj> + ||xj||^2 over one j-tile.
// grid: ((K_PTS/ICH)*JS, B_SZ), block: 256. ws[((b*JS+js)*3+s)*K_PTS + i].
__global__ __launch_bounds__(256) void sor_partial(
    const float* __restrict__ x, float* __restrict__ ws)
{
    __shared__ float4 pts[JT];   // 8 KiB: (x, y, z, ||x||^2)
    const int b  = blockIdx.y;
    const int js = blockIdx.x & (JS - 1);
    const int ic = blockIdx.x / JS;
    const int j0 = js * JT;
    const float* xb = x + (size_t)b * K_PTS * 3;

    for (int p = threadIdx.x; p < JT; p += THR) {
        float a0 = xb[(j0 + p) * 3 + 0];
        float a1 = xb[(j0 + p) * 3 + 1];
        float a2 = xb[(j0 + p) * 3 + 2];
        pts[p] = make_float4(a0, a1, a2, a0 * a0 + a1 * a1 + a2 * a2);
    }
    __syncthreads();

    const int ibase = ic * ICH + threadIdx.x;
    float x2[IPT], y2[IPT], z2[IPT];          // -2 * xi
    float m0[IPT], m1[IPT], m2[IPT];
    #pragma unroll
    for (int k = 0; k < IPT; ++k) {
        const int i = ibase + k * THR;
        x2[k] = -2.0f * xb[i * 3 + 0];
        y2[k] = -2.0f * xb[i * 3 + 1];
        z2[k] = -2.0f * xb[i * 3 + 2];
        m0[k] = BIGF; m1[k] = BIGF; m2[k] = BIGF;
    }

    #pragma unroll 4
    for (int j = 0; j < JT; ++j) {
        const float4 pj = pts[j];
        #pragma unroll
        for (int k = 0; k < IPT; ++k) {
            float t = fmaf(z2[k], pj.z, pj.w);
            t = fmaf(y2[k], pj.y, t);
            float d = fmaf(x2[k], pj.x, t);   // d' = -2 dot + ||xj||^2
            insert3(d, m0[k], m1[k], m2[k]);
        }
    }

    #pragma unroll
    for (int k = 0; k < IPT; ++k) {
        const int i = ibase + k * THR;
        float* w = ws + (size_t)((b * JS + js) * 3) * K_PTS + i;
        w[0]          = m0[k];
        w[K_PTS]      = m1[k];
        w[2 * K_PTS]  = m2[k];
    }
}

// Merge JS partial triples per point -> mean of 2NN distances (self dropped at m0).
__global__ __launch_bounds__(256) void sor_merge(
    const float* __restrict__ x, const float* __restrict__ ws,
    float* __restrict__ value)
{
    const int gid = blockIdx.x * 256 + threadIdx.x;   // 0 .. B*K-1
    const int b = gid >> 12;
    const int i = gid & (K_PTS - 1);

    float m0 = BIGF, m1 = BIGF, m2 = BIGF;
    #pragma unroll
    for (int js = 0; js < JS; ++js) {
        #pragma unroll
        for (int s = 0; s < 3; ++s) {
            float d = ws[(size_t)((b * JS + js) * 3 + s) * K_PTS + i];
            insert3(d, m0, m1, m2);
        }
    }
    const float a0 = x[(size_t)gid * 3 + 0];
    const float a1 = x[(size_t)gid * 3 + 1];
    const float a2 = x[(size_t)gid * 3 + 2];
    const float xx = a0 * a0 + a1 * a1 + a2 * a2;
    // un-shift: true distances are m' + ||xi||^2; m0 is self (global min).
    value[gid] = ((m1 + xx) + (m2 + xx)) * 0.5f;
}

// One block per batch: mean/std(ddof=1) -> threshold -> mask + zeroed points.
__global__ __launch_bounds__(1024) void sor_mask_kernel(
    const float* __restrict__ x, float* __restrict__ out)
{
    const int b = blockIdx.x;
    const int tid = threadIdx.x;
    float* value = out + (size_t)B_SZ * K_PTS * 3;
    float* selpc = out;

    __shared__ float red[16];
    __shared__ float sh_mean, sh_thr;

    float v[4];
    float s = 0.0f;
    #pragma unroll
    for (int k = 0; k < 4; ++k) {
        v[k] = value[b * K_PTS + tid + k * 1024];
        s += v[k];
    }
    #pragma unroll
    for (int off = 32; off > 0; off >>= 1) s += __shfl_down(s, off, 64);
    if ((tid & 63) == 0) red[tid >> 6] = s;
    __syncthreads();
    if (tid == 0) {
        float t = 0.0f;
        for (int w = 0; w < 16; ++w) t += red[w];
        sh_mean = t * (1.0f / (float)K_PTS);
    }
    __syncthreads();
    const float mean = sh_mean;

    float q = 0.0f;
    #pragma unroll
    for (int k = 0; k < 4; ++k) { float dv = v[k] - mean; q += dv * dv; }
    #pragma unroll
    for (int off = 32; off > 0; off >>= 1) q += __shfl_down(q, off, 64);
    if ((tid & 63) == 0) red[tid >> 6] = q;
    __syncthreads();
    if (tid == 0) {
        float t = 0.0f;
        for (int w = 0; w < 16; ++w) t += red[w];
        sh_thr = mean + ALPHA * sqrtf(t / (float)(K_PTS - 1));
    }
    __syncthreads();
    const float thr = sh_thr;

    #pragma unroll
    for (int k = 0; k < 4; ++k) {
        const int i = tid + k * 1024;
        const bool keep = v[k] <= thr;
        value[b * K_PTS + i] = keep ? 1.0f : 0.0f;
        const size_t base = ((size_t)b * K_PTS + i) * 3;
        float x0 = x[base + 0];
        float x1 = x[base + 1];
        float x2 = x[base + 2];
        selpc[base + 0] = keep ? x0 : 0.0f;
        selpc[base + 1] = keep ? x1 : 0.0f;
        selpc[base + 2] = keep ? x2 : 0.0f;
    }
}

// ---- Fallback (round-1 kernel) used only if d_ws is too small ----
__global__ __launch_bounds__(256) void sor_value_kernel(
    const float* __restrict__ x, float* __restrict__ value)
{
    __shared__ float4 pts[K_PTS];
    const int b = blockIdx.y;
    const float* xb = x + (size_t)b * K_PTS * 3;
    for (int p = threadIdx.x; p < K_PTS; p += 256) {
        float a0 = xb[p * 3 + 0];
        float a1 = xb[p * 3 + 1];
        float a2 = xb[p * 3 + 2];
        pts[p] = make_float4(a0, a1, a2, a0 * a0 + a1 * a1 + a2 * a2);
    }
    __syncthreads();
    const int i = blockIdx.x * 256 + threadIdx.x;
    const float4 pi = pts[i];
    float m0 = BIGF, m1 = BIGF, m2 = BIGF;
    #pragma unroll 8
    for (int j = 0; j < K_PTS; ++j) {
        float4 pj = pts[j];
        float dot = pi.x * pj.x + pi.y * pj.y + pi.z * pj.z;
        float d = (pi.w - 2.0f * dot) + pj.w;
        insert3(d, m0, m1, m2);
    }
    value[b * K_PTS + i] = 0.5f * (m1 + m2);
}

extern "C" void kernel_launch(void* const* d_in, const int* in_sizes, int n_in,
                              void* d_out, int out_size, void* d_ws, size_t ws_size,
                              hipStream_t stream)
{
    const float* x = (const float*)d_in[0];
    float* out = (float*)d_out;
    float* value = out + (size_t)B_SZ * K_PTS * 3;
    const size_t ws_needed = (size_t)B_SZ * JS * 3 * K_PTS * sizeof(float); // 6 MiB

    if (ws_size >= ws_needed) {
        float* ws = (float*)d_ws;
        dim3 gA((K_PTS / ICH) * JS, B_SZ);                 // (32, 16) = 512 blocks
        sor_partial<<<gA, THR, 0, stream>>>(x, ws);
        sor_merge<<<(B_SZ * K_PTS) / 256, 256, 0, stream>>>(x, ws, value);
    } else {
        dim3 g1(K_PTS / 256, B_SZ);
        sor_value_kernel<<<g1, 256, 0, stream>>>(x, value);
    }
    sor_mask_kernel<<<B_SZ, 1024, 0, stream>>>(x, out);
}